// Round 8
// baseline (91.780 us; speedup 1.0000x reference)
//
#include <hip/hip_runtime.h>

// LinearAttention: B=1, H=16, N=2048, D=DV=64, causal=1, f32 in/out.
// Two dispatches:
//  k1: per-chunk S_c^T (bf16, z_c folded as row 64) + Kf row-major bf16 +
//      V^T bf16 streamed to ws (pass-through for k2).
//  k2: per-block batched prefix reduction over predecessor chunks (f32 regs,
//      8 loads in flight, predicated accumulate), then W = mask(Qf Kf^T),
//      O = W V + Qf S_pre, den fused as extra column.
#define Hh   16
#define Nn   2048
#define Dd   64
#define DVv  64
#define Ll   64
#define Cc   (Nn / Ll)      // 32
#define HCc  (Hh * Cc)      // 512
#define CS   (65 * 64)      // ws chunk stride: 64 S^T rows + 1 z row
#define EPSf 1e-6f
#define LDP  72             // bf16 row stride (+8 pad, keeps 16B align)

typedef __attribute__((ext_vector_type(8))) __bf16 bf16x8;
typedef __attribute__((ext_vector_type(4))) __bf16 bf16x4;
typedef __attribute__((ext_vector_type(4))) float  f32x4;

__device__ __forceinline__ float fmap(float x) {
    return x > 0.0f ? (x + 1.0f) : __expf(x);   // elu(x)+1
}
__device__ __forceinline__ __bf16 tobf(float x) { return (__bf16)x; }

// ---------------- k1: S_c^T + z row (bf16) ; Kf, V^T pass-through ----------
__global__ __launch_bounds__(256) void k_chunk_sums(
    const float* __restrict__ Kg, const float* __restrict__ Vg,
    __bf16* __restrict__ Sws, __bf16* __restrict__ Kfb,
    __bf16* __restrict__ Vtb)
{
    __shared__ __align__(16) __bf16 sKT[Dd][LDP];   // Kf^T: [d][m]
    __shared__ __align__(16) __bf16 sVT[80][LDP];   // V^T: [e][m]; row 64 = ones
    const int t  = threadIdx.x;
    const int hc = blockIdx.x;
    const float4* K4 = (const float4*)(Kg + (size_t)hc * (Ll * Dd));
    const float4* V4 = (const float4*)(Vg + (size_t)hc * (Ll * DVv));
    __bf16* Kfo = Kfb + (size_t)hc * (Ll * Dd);
    for (int i = t; i < (Ll * Dd) / 4; i += 256) {   // 4 iters
        float4 k4 = K4[i];
        float4 v4 = V4[i];
        const int m  = i >> 4;
        const int c0 = (i & 15) * 4;
        bf16x4 kv = { tobf(fmap(k4.x)), tobf(fmap(k4.y)), tobf(fmap(k4.z)), tobf(fmap(k4.w)) };
        sKT[c0 + 0][m] = kv[0];
        sKT[c0 + 1][m] = kv[1];
        sKT[c0 + 2][m] = kv[2];
        sKT[c0 + 3][m] = kv[3];
        *(bf16x4*)&Kfo[m * Dd + c0] = kv;            // coalesced 8-B stores
        sVT[c0 + 0][m] = tobf(v4.x);
        sVT[c0 + 1][m] = tobf(v4.y);
        sVT[c0 + 2][m] = tobf(v4.z);
        sVT[c0 + 3][m] = tobf(v4.w);
    }
    for (int i = t; i < 16 * LDP; i += 256) {        // aux rows 64..79
        const int r = i / LDP, c = i % LDP;
        sVT[64 + r][c] = (r == 0) ? (__bf16)1.0f : (__bf16)0.0f;
    }
    __syncthreads();

    const int lane = t & 63, wv = t >> 6;
    const int col = lane & 15, quad = lane >> 4;
    __bf16* So = Sws + (size_t)hc * CS;              // [e][d], row 64 = z
    for (int et = 0; et < 5; ++et) {
        f32x4 acc = {0.f, 0.f, 0.f, 0.f};
#pragma unroll
        for (int ks = 0; ks < 2; ++ks) {
            bf16x8 a = *(const bf16x8*)&sKT[wv * 16 + col][ks * 32 + quad * 8];
            bf16x8 b = *(const bf16x8*)&sVT[et * 16 + col][ks * 32 + quad * 8];
            acc = __builtin_amdgcn_mfma_f32_16x16x32_bf16(a, b, acc, 0, 0, 0);
        }
        bf16x4 s4 = { tobf(acc[0]), tobf(acc[1]), tobf(acc[2]), tobf(acc[3]) };
        const int d = wv * 16 + quad * 4;
        if (et < 4) {
            *(bf16x4*)&So[(et * 16 + col) * Dd + d] = s4;
        } else if (col == 0) {
            *(bf16x4*)&So[64 * Dd + d] = s4;         // z row
        }
    }
    // Dump V^T (bf16) for k2's bV staging (coalesced 16-B stores from LDS)
    __bf16* Vto = Vtb + (size_t)hc * (Ll * DVv);
    for (int i = t; i < (Ll * DVv) / 8; i += 256) {  // 2 iters
        const int e = i >> 3, m0 = (i & 7) * 8;
        *(bf16x8*)&Vto[e * Ll + m0] = *(const bf16x8*)&sVT[e][m0];
    }
}

// ---------------- k2: batched prefix + W-GEMM + O-GEMM ----------------
__global__ __launch_bounds__(256) void k_output(
    const float* __restrict__ Qg, const __bf16* __restrict__ Kfb,
    const __bf16* __restrict__ Vtb, const __bf16* __restrict__ Sws,
    float* __restrict__ Og)
{
    __shared__ __align__(16) __bf16 aQ[Ll][LDP];    // Qf rows (A)
    __shared__ __align__(16) __bf16 aK[Ll][LDP];    // Kf rows (B^T for W-GEMM)
    __shared__ __align__(16) __bf16 sW[Ll][LDP];    // masked W (A for O-GEMM)
    __shared__ __align__(16) __bf16 bV[80][LDP];    // V^T; row 64 = ones
    __shared__ __align__(16) __bf16 bS[80][LDP];    // Spre^T; row 64 = z_pre
    const int t  = threadIdx.x;
    const int hc = blockIdx.x;
    const int h  = hc >> 5, c = hc & 31;
    const int lane = t & 63, wv = t >> 6;
    const int col = lane & 15, quad = lane >> 4;

    // Prefix over predecessor chunks: thread handles slices sl, sl+256 (8 elems each).
    // Loads are unconditional within ceil(c/8) batches (8 in flight); accumulation
    // predicated on cc < c. f32 accumulation, single bf16 rounding at LDS write.
    {
        const __bf16* Sh = Sws + (size_t)h * Cc * CS;
        const int nb = (c + 7) >> 3;
        for (int sl = t; sl < CS / 8; sl += 256) {   // 520 slices
            float run[8];
#pragma unroll
            for (int j = 0; j < 8; ++j) run[j] = 0.0f;
            for (int cb = 0; cb < nb; ++cb) {
                bf16x8 v[8];
#pragma unroll
                for (int k = 0; k < 8; ++k)
                    v[k] = *(const bf16x8*)(Sh + (size_t)(cb * 8 + k) * CS + sl * 8);
#pragma unroll
                for (int k = 0; k < 8; ++k) {
                    if (cb * 8 + k < c) {
#pragma unroll
                        for (int j = 0; j < 8; ++j) run[j] += (float)v[k][j];
                    }
                }
            }
            bf16x8 o;
#pragma unroll
            for (int j = 0; j < 8; ++j) o[j] = tobf(run[j]);
            const int e = sl >> 3, d0 = (sl & 7) * 8;
            *(bf16x8*)&bS[e][d0] = o;                // rows 0..63 = S^T, row 64 = z
        }
    }

    // Stage Qf (f32 + fmap) and Kf / V^T (bf16x8 -> ds_write_b128)
    {
        const float4* Q4 = (const float4*)(Qg + (size_t)hc * (Ll * Dd));
        for (int i = t; i < (Ll * Dd) / 4; i += 256) {
            float4 q4 = Q4[i];
            const int m  = i >> 4;
            const int c0 = (i & 15) * 4;
            bf16x4 qv = { tobf(fmap(q4.x)), tobf(fmap(q4.y)), tobf(fmap(q4.z)), tobf(fmap(q4.w)) };
            *(bf16x4*)&aQ[m][c0] = qv;
        }
        const __bf16* Kfo = Kfb + (size_t)hc * (Ll * Dd);
        const __bf16* Vto = Vtb + (size_t)hc * (Ll * DVv);
        for (int i = t; i < (Ll * Dd) / 8; i += 256) {   // 2 iters
            const int r = i >> 3, c0 = (i & 7) * 8;
            *(bf16x8*)&aK[r][c0] = *(const bf16x8*)(Kfo + i * 8);
            *(bf16x8*)&bV[r][c0] = *(const bf16x8*)(Vto + i * 8);
        }
        for (int i = t; i < 16 * LDP; i += 256) {        // aux rows
            const int r = i / LDP, cc = i % LDP;
            bV[64 + r][cc] = (r == 0) ? (__bf16)1.0f : (__bf16)0.0f;
            if (r > 0) bS[64 + r][cc] = (__bf16)0.0f;
        }
    }
    __syncthreads();

    // W-GEMM: W = mask(Qf Kf^T)
#pragma unroll 1
    for (int mt = 0; mt < 4; ++mt) {
        f32x4 wacc = {0.f, 0.f, 0.f, 0.f};
#pragma unroll
        for (int ks = 0; ks < 2; ++ks) {
            bf16x8 a = *(const bf16x8*)&aQ[wv * 16 + col][ks * 32 + quad * 8];
            bf16x8 b = *(const bf16x8*)&aK[mt * 16 + col][ks * 32 + quad * 8];
            wacc = __builtin_amdgcn_mfma_f32_16x16x32_bf16(a, b, wacc, 0, 0, 0);
        }
#pragma unroll
        for (int j = 0; j < 4; ++j) {
            const int n = wv * 16 + quad * 4 + j;
            const int m = mt * 16 + col;
            sW[n][m] = tobf(m <= n ? wacc[j] : 0.0f);
        }
    }
    __syncthreads();

    // O-GEMM: acc[et] = W.(V^T block) + Qf.(Spre^T block); et=4 -> den
    f32x4 accs[5];
#pragma unroll 1
    for (int et = 0; et < 5; ++et) {
        f32x4 acc = {0.f, 0.f, 0.f, 0.f};
#pragma unroll
        for (int ks = 0; ks < 2; ++ks) {
            bf16x8 a = *(const bf16x8*)&sW[wv * 16 + col][ks * 32 + quad * 8];
            bf16x8 b = *(const bf16x8*)&bV[et * 16 + col][ks * 32 + quad * 8];
            acc = __builtin_amdgcn_mfma_f32_16x16x32_bf16(a, b, acc, 0, 0, 0);
        }
#pragma unroll
        for (int ks = 0; ks < 2; ++ks) {
            bf16x8 a = *(const bf16x8*)&aQ[wv * 16 + col][ks * 32 + quad * 8];
            bf16x8 b = *(const bf16x8*)&bS[et * 16 + col][ks * 32 + quad * 8];
            acc = __builtin_amdgcn_mfma_f32_16x16x32_bf16(a, b, acc, 0, 0, 0);
        }
        accs[et] = acc;
    }
    float dn[4];
#pragma unroll
    for (int j = 0; j < 4; ++j) dn[j] = __shfl(accs[4][j], lane & 48);

    float* Oc = Og + (size_t)hc * (Ll * DVv);
#pragma unroll
    for (int et = 0; et < 4; ++et) {
#pragma unroll
        for (int j = 0; j < 4; ++j) {
            const int n = wv * 16 + quad * 4 + j;
            Oc[n * DVv + et * 16 + col] = accs[et][j] / (dn[j] + EPSf);
        }
    }
}

extern "C" void kernel_launch(void* const* d_in, const int* in_sizes, int n_in,
                              void* d_out, int out_size, void* d_ws, size_t ws_size,
                              hipStream_t stream) {
    const float* Q = (const float*)d_in[0];
    const float* K = (const float*)d_in[1];
    const float* V = (const float*)d_in[2];
    unsigned char* ws = (unsigned char*)d_ws;
    __bf16* Sws = (__bf16*)ws;                                   // 512*4160*2 = 4.26 MB
    __bf16* Kfb = (__bf16*)(ws + (size_t)HCc * CS * 2);          // 4.19 MB
    __bf16* Vtb = Kfb + (size_t)HCc * Ll * Dd;                   // 4.19 MB
    float* out = (float*)d_out;

    k_chunk_sums<<<HCc, 256, 0, stream>>>(K, V, Sws, Kfb, Vtb);
    k_output<<<HCc, 256, 0, stream>>>(Q, Kfb, Vtb, Sws, out);
}

// Round 9
// 88.691 us; speedup vs baseline: 1.0348x; 1.0348x over previous
//
#include <hip/hip_runtime.h>

// LinearAttention: B=1, H=16, N=2048, D=DV=64, causal=1, f32 in/out.
// Three dispatches (measured-best structure, R5):
//  k1: per-chunk S_c^T = (Kf^T V)^T in bf16, z_c = colsum(Kf) f32.
//  kp: batched exclusive prefix scan over chunk axis (in-place, bf16).
//  k2: W = mask(Qf Kf^T), O = W V + Qf S_pre, den fused as extra column.
// Measured bracketing (R2-R8): any fusion of these via grid.sync (225us),
// device-fence election (161us), or per-consumer redundant prefix (92-95us)
// regresses vs the 3-dispatch form (88.9us). Do not re-fuse.
#define Hh   16
#define Nn   2048
#define Dd   64
#define DVv  64
#define Ll   64
#define Cc   (Nn / Ll)      // 32
#define HCc  (Hh * Cc)      // 512
#define EPSf 1e-6f
#define LDP  72             // bf16 row stride (+8 pad, keeps 16B align)

typedef __attribute__((ext_vector_type(8))) __bf16 bf16x8;
typedef __attribute__((ext_vector_type(4))) __bf16 bf16x4;
typedef __attribute__((ext_vector_type(4))) float  f32x4;

__device__ __forceinline__ float fmap(float x) {
    return x > 0.0f ? (x + 1.0f) : __expf(x);   // elu(x)+1
}
__device__ __forceinline__ __bf16 tobf(float x) { return (__bf16)x; }

// ---------------- k1: S_c^T (bf16) + z_c (f32) ----------------
__global__ __launch_bounds__(256) void k_chunk_sums(
    const float* __restrict__ Kg, const float* __restrict__ Vg,
    __bf16* __restrict__ SwsT, float* __restrict__ zws)
{
    __shared__ __align__(16) __bf16 sKT[Dd][LDP];   // Kf^T: [d][m]
    __shared__ __align__(16) __bf16 sVT[80][LDP];   // V^T: [e][m]; row 64 = ones
    const int t  = threadIdx.x;
    const int hc = blockIdx.x;
    const float4* K4 = (const float4*)(Kg + (size_t)hc * (Ll * Dd));
    const float4* V4 = (const float4*)(Vg + (size_t)hc * (Ll * DVv));
    for (int i = t; i < (Ll * Dd) / 4; i += 256) {   // 4 iters
        float4 k4 = K4[i];
        float4 v4 = V4[i];
        const int m  = i >> 4;
        const int c0 = (i & 15) * 4;
        sKT[c0 + 0][m] = tobf(fmap(k4.x));
        sKT[c0 + 1][m] = tobf(fmap(k4.y));
        sKT[c0 + 2][m] = tobf(fmap(k4.z));
        sKT[c0 + 3][m] = tobf(fmap(k4.w));
        sVT[c0 + 0][m] = tobf(v4.x);
        sVT[c0 + 1][m] = tobf(v4.y);
        sVT[c0 + 2][m] = tobf(v4.z);
        sVT[c0 + 3][m] = tobf(v4.w);
    }
    for (int i = t; i < 16 * LDP; i += 256) {        // aux rows 64..79
        const int r = i / LDP, c = i % LDP;
        sVT[64 + r][c] = (r == 0) ? (__bf16)1.0f : (__bf16)0.0f;
    }
    __syncthreads();

    const int lane = t & 63, wv = t >> 6;
    const int col = lane & 15, quad = lane >> 4;
    __bf16* So = SwsT + (size_t)hc * (Dd * DVv);     // S^T layout: [e][d]
    for (int et = 0; et < 5; ++et) {
        f32x4 acc = {0.f, 0.f, 0.f, 0.f};
#pragma unroll
        for (int ks = 0; ks < 2; ++ks) {
            bf16x8 a = *(const bf16x8*)&sKT[wv * 16 + col][ks * 32 + quad * 8];
            bf16x8 b = *(const bf16x8*)&sVT[et * 16 + col][ks * 32 + quad * 8];
            acc = __builtin_amdgcn_mfma_f32_16x16x32_bf16(a, b, acc, 0, 0, 0);
        }
        if (et < 4) {
            const int e = et * 16 + col;
            const int d = wv * 16 + quad * 4;
            bf16x4 s4 = { tobf(acc[0]), tobf(acc[1]), tobf(acc[2]), tobf(acc[3]) };
            *(bf16x4*)&So[e * Dd + d] = s4;
        } else if (col == 0) {
#pragma unroll
            for (int j = 0; j < 4; ++j)
                zws[hc * Dd + wv * 16 + quad * 4 + j] = acc[j];
        }
    }
}

// ---------------- kp: exclusive prefix over chunk axis, batched loads ---------
// Blocks 0..31: S^T slices (8192 threads x 16B). Blocks 32..35: z scans.
__global__ __launch_bounds__(256) void k_prefix(
    __bf16* __restrict__ SwsT, float* __restrict__ zws)
{
    const int b = blockIdx.x, t = threadIdx.x;
    if (b < 32) {
        const int gid = b * 256 + t;              // [0, 8192)
        const int h   = gid >> 9;                 // 512 slices per head
        const int sl  = gid & 511;
        __bf16* base = SwsT + ((size_t)h * Cc) * (Dd * DVv) + sl * 8;
        float run[8];
#pragma unroll
        for (int j = 0; j < 8; ++j) run[j] = 0.0f;
#pragma unroll
        for (int cb = 0; cb < 4; ++cb) {          // 4 batches of 8 chunks
            bf16x8 v[8];
#pragma unroll
            for (int k = 0; k < 8; ++k)
                v[k] = *(const bf16x8*)(base + (size_t)(cb * 8 + k) * (Dd * DVv));
#pragma unroll
            for (int k = 0; k < 8; ++k) {
                bf16x8 o;
#pragma unroll
                for (int j = 0; j < 8; ++j) {
                    o[j] = tobf(run[j]);
                    run[j] += (float)v[k][j];
                }
                *(bf16x8*)(base + (size_t)(cb * 8 + k) * (Dd * DVv)) = o;
            }
        }
    } else {
        const int gid = (b - 32) * 256 + t;       // [0, 1024)
        const int h = gid >> 6, d = gid & 63;
        float* zb = zws + (h * Cc) * Dd + d;
        float run = 0.0f;
#pragma unroll
        for (int cb = 0; cb < 4; ++cb) {
            float v[8];
#pragma unroll
            for (int k = 0; k < 8; ++k) v[k] = zb[(cb * 8 + k) * Dd];
#pragma unroll
            for (int k = 0; k < 8; ++k) {
                zb[(cb * 8 + k) * Dd] = run;
                run += v[k];
            }
        }
    }
}

// ---------------- k2: W-GEMM + O-GEMM, S_pre staged from ws ----------------
__global__ __launch_bounds__(256) void k_output(
    const float* __restrict__ Qg, const float* __restrict__ Kg,
    const float* __restrict__ Vg, const __bf16* __restrict__ SwsT,
    const float* __restrict__ zws, float* __restrict__ Og)
{
    __shared__ __align__(16) __bf16 aQ[Ll][LDP];    // Qf rows (A)
    __shared__ __align__(16) __bf16 aK[Ll][LDP];    // Kf rows (B^T for W-GEMM)
    __shared__ __align__(16) __bf16 sW[Ll][LDP];    // masked W (A for O-GEMM)
    __shared__ __align__(16) __bf16 bV[80][LDP];    // V^T; row 64 = ones
    __shared__ __align__(16) __bf16 bS[80][LDP];    // Spre^T; row 64 = z_pre
    const int t  = threadIdx.x;
    const int hc = blockIdx.x;
    const int lane = t & 63, wv = t >> 6;
    const int col = lane & 15, quad = lane >> 4;

    // Stage Qf / Kf / V^T
    {
        const float4* Q4 = (const float4*)(Qg + (size_t)hc * (Ll * Dd));
        const float4* K4 = (const float4*)(Kg + (size_t)hc * (Ll * Dd));
        const float4* V4 = (const float4*)(Vg + (size_t)hc * (Ll * DVv));
        for (int i = t; i < (Ll * Dd) / 4; i += 256) {
            float4 q4 = Q4[i];
            float4 k4 = K4[i];
            float4 v4 = V4[i];
            const int m  = i >> 4;
            const int c0 = (i & 15) * 4;
            bf16x4 qv = { tobf(fmap(q4.x)), tobf(fmap(q4.y)), tobf(fmap(q4.z)), tobf(fmap(q4.w)) };
            bf16x4 kv = { tobf(fmap(k4.x)), tobf(fmap(k4.y)), tobf(fmap(k4.z)), tobf(fmap(k4.w)) };
            *(bf16x4*)&aQ[m][c0] = qv;
            *(bf16x4*)&aK[m][c0] = kv;
            bV[c0 + 0][m] = tobf(v4.x);
            bV[c0 + 1][m] = tobf(v4.y);
            bV[c0 + 2][m] = tobf(v4.z);
            bV[c0 + 3][m] = tobf(v4.w);
        }
        for (int i = t; i < 16 * LDP; i += 256) {
            const int r = i / LDP, cc = i % LDP;
            bV[64 + r][cc] = (r == 0) ? (__bf16)1.0f : (__bf16)0.0f;
        }
    }

    // Stage S_pre^T (bf16, vectorized) + z_pre row
    {
        const __bf16* Sp = SwsT + (size_t)hc * (Dd * DVv);
        for (int i = t; i < (Dd * DVv) / 8; i += 256) {   // 2 iters
            bf16x8 s = *(const bf16x8*)(Sp + i * 8);
            const int e = i >> 3, d0 = (i & 7) * 8;
            *(bf16x8*)&bS[e][d0] = s;
        }
        if (t < Dd) bS[64][t] = tobf(zws[hc * Dd + t]);
        for (int i = t; i < 16 * LDP; i += 256) {
            const int r = i / LDP, cc = i % LDP;
            if (!(r == 0 && cc < Dd)) bS[64 + r][cc] = (__bf16)0.0f;
        }
    }
    __syncthreads();

    // W-GEMM: W = mask(Qf Kf^T)
#pragma unroll 1
    for (int mt = 0; mt < 4; ++mt) {
        f32x4 wacc = {0.f, 0.f, 0.f, 0.f};
#pragma unroll
        for (int ks = 0; ks < 2; ++ks) {
            bf16x8 a = *(const bf16x8*)&aQ[wv * 16 + col][ks * 32 + quad * 8];
            bf16x8 b = *(const bf16x8*)&aK[mt * 16 + col][ks * 32 + quad * 8];
            wacc = __builtin_amdgcn_mfma_f32_16x16x32_bf16(a, b, wacc, 0, 0, 0);
        }
#pragma unroll
        for (int j = 0; j < 4; ++j) {
            const int n = wv * 16 + quad * 4 + j;
            const int m = mt * 16 + col;
            sW[n][m] = tobf(m <= n ? wacc[j] : 0.0f);
        }
    }
    __syncthreads();

    // O-GEMM: acc[et] = W.(V^T block) + Qf.(Spre^T block); et=4 -> den
    f32x4 accs[5];
#pragma unroll 1
    for (int et = 0; et < 5; ++et) {
        f32x4 acc = {0.f, 0.f, 0.f, 0.f};
#pragma unroll
        for (int ks = 0; ks < 2; ++ks) {
            bf16x8 a = *(const bf16x8*)&sW[wv * 16 + col][ks * 32 + quad * 8];
            bf16x8 b = *(const bf16x8*)&bV[et * 16 + col][ks * 32 + quad * 8];
            acc = __builtin_amdgcn_mfma_f32_16x16x32_bf16(a, b, acc, 0, 0, 0);
        }
#pragma unroll
        for (int ks = 0; ks < 2; ++ks) {
            bf16x8 a = *(const bf16x8*)&aQ[wv * 16 + col][ks * 32 + quad * 8];
            bf16x8 b = *(const bf16x8*)&bS[et * 16 + col][ks * 32 + quad * 8];
            acc = __builtin_amdgcn_mfma_f32_16x16x32_bf16(a, b, acc, 0, 0, 0);
        }
        accs[et] = acc;
    }
    float dn[4];
#pragma unroll
    for (int j = 0; j < 4; ++j) dn[j] = __shfl(accs[4][j], lane & 48);

    float* Oc = Og + (size_t)hc * (Ll * DVv);
#pragma unroll
    for (int et = 0; et < 4; ++et) {
#pragma unroll
        for (int j = 0; j < 4; ++j) {
            const int n = wv * 16 + quad * 4 + j;
            Oc[n * DVv + et * 16 + col] = accs[et][j] / (dn[j] + EPSf);
        }
    }
}

extern "C" void kernel_launch(void* const* d_in, const int* in_sizes, int n_in,
                              void* d_out, int out_size, void* d_ws, size_t ws_size,
                              hipStream_t stream) {
    const float* Q = (const float*)d_in[0];
    const float* K = (const float*)d_in[1];
    const float* V = (const float*)d_in[2];
    __bf16* SwsT = (__bf16*)d_ws;                        // HC * 4096 bf16 = 4.2 MB
    float*  zws  = (float*)((char*)d_ws + (size_t)HCc * Dd * DVv * sizeof(__bf16));
    float* out = (float*)d_out;

    k_chunk_sums<<<HCc, 256, 0, stream>>>(K, V, SwsT, zws);
    k_prefix<<<36, 256, 0, stream>>>(SwsT, zws);
    k_output<<<HCc, 256, 0, stream>>>(Q, K, V, SwsT, zws, out);
}